// Round 1
// 257.219 us; speedup vs baseline: 1.1097x; 1.1097x over previous
//
#include <hip/hip_runtime.h>

#define NN 100000
#define NE 3200000
#define NF 128
#define C1 32
#define C2 16
#define NG 64
#define BKT_SH 7
#define BKT_W  128
#define NBKT   782          // ceil(NN/128)
#define CH     8192         // edges per partition chunk
#define NW     391          // ceil(NE/CH)
#define RSTR   784          // runstart row stride (783 used)
#define MAPCAP 6400         // per-bucket flattened-edge capacity (mean 4092, sd 64)

// ---- workspace layout (4-byte element offsets) ----
#define OFF_BCNT  0            // 1024 ints (782 used)
#define OFF_BST   1024         // 1024 ints (783 used)
#define OFF_RUN   2048         // NW*RSTR = 306,544 ints
#define OFF_ROW   308608       // NN+1 ints
#define OFF_DIS   408624       // NN floats
#define OFF_POOL  508624       // NG*C2 floats
#define OFF_CNTF  509648       // NG floats (+pad)
#define OFF_EDG   509712       // NE uints (dead after fillfused)
#define OFF_XS1   OFF_EDG                  // NN*16 uints bf16x2 cols 0..31 (aliases edgebuf)
#define OFF_XS2B  (OFF_EDG + NE)           // NN*8 uints bf16x2
#define OFF_COL   (OFF_XS2B + NN*8)        // NE ints CSR col indices

// ---- bf16x2 pack/unpack (RNE) ----
__device__ __forceinline__ unsigned pack_bf2(float a, float b) {
    unsigned ua = __float_as_uint(a);
    unsigned ub = __float_as_uint(b);
    ua = (ua + 0x7fffu + ((ua >> 16) & 1u)) >> 16;
    ub = (ub + 0x7fffu + ((ub >> 16) & 1u)) & 0xffff0000u;
    return ua | ub;   // lo = a, hi = b
}
__device__ __forceinline__ float2 unpack_bf2(unsigned u) {
    return make_float2(__uint_as_float(u << 16), __uint_as_float(u & 0xffff0000u));
}
__device__ __forceinline__ void acc4(float4& a, uint2 q) {
    float2 f0 = unpack_bf2(q.x), f1 = unpack_bf2(q.y);
    a.x += f0.x; a.y += f0.y; a.z += f1.x; a.w += f1.y;
}

// ---------------- k_part: per-chunk counting sort by bucket -----------------
// 512 threads: halves serial loops; wave-shuffle scan kills 15 of 16 barriers.
__global__ __launch_bounds__(512) void k_part(
    const int* __restrict__ S, const int* __restrict__ D,
    unsigned* __restrict__ edgebuf, int* __restrict__ runstart,
    int* __restrict__ bcnt)
{
    __shared__ int lhist[1024];
    __shared__ int lstart[1024];
    __shared__ int lcur[NBKT];
    __shared__ int wsum[8];
    __shared__ unsigned lsort[CH];
    const int w = blockIdx.x;
    const int t = threadIdx.x;
    const int e0 = w * CH;
    const int n = min(CH, NE - e0);

    for (int i = t; i < 1024; i += 512) lhist[i] = 0;
    __syncthreads();
    for (int i = t; i < n; i += 512)
        atomicAdd(&lhist[(unsigned)D[e0 + i] >> BKT_SH], 1);
    __syncthreads();
    for (int i = t; i < NBKT; i += 512) atomicAdd(&bcnt[i], lhist[i]);

    // exclusive scan of 1024 hist entries: 2 per thread, wave-shuffle scan
    int c0 = lhist[t * 2 + 0], c1 = lhist[t * 2 + 1];
    int ts = c0 + c1;
    const int lane = t & 63, wv = t >> 6;
    int sc = ts;
    #pragma unroll
    for (int off = 1; off < 64; off <<= 1) {
        int v = __shfl_up(sc, off, 64);
        if (lane >= off) sc += v;
    }
    if (lane == 63) wsum[wv] = sc;
    __syncthreads();
    int wo = 0;
    #pragma unroll
    for (int i = 0; i < 8; ++i) wo += (i < wv) ? wsum[i] : 0;
    int excl = sc - ts + wo;
    lstart[t * 2 + 0] = excl;
    lstart[t * 2 + 1] = excl + c0;
    __syncthreads();

    for (int i = t; i < 783; i += 512) runstart[w * RSTR + i] = lstart[i];
    for (int i = t; i < NBKT; i += 512) lcur[i] = lstart[i];
    __syncthreads();
    for (int i = t; i < n; i += 512) {
        int s = S[e0 + i], d = D[e0 + i];
        int pos = atomicAdd(&lcur[(unsigned)d >> BKT_SH], 1);
        lsort[pos] = ((unsigned)s << BKT_SH) | (unsigned)(d & (BKT_W - 1));
    }
    __syncthreads();
    for (int i = t; i < n; i += 512) edgebuf[e0 + i] = lsort[i];
}

// ---------------- scan 782 bucket totals (single WG) ----------------
__global__ __launch_bounds__(256) void k_bscan(const int* __restrict__ bcnt,
                                               int* __restrict__ bstart,
                                               int* __restrict__ rowstart) {
    __shared__ int sd[256];
    const int t = threadIdx.x;
    const int base = t * 4;
    int c0 = (base + 0 < NBKT) ? bcnt[base + 0] : 0;
    int c1 = (base + 1 < NBKT) ? bcnt[base + 1] : 0;
    int c2 = (base + 2 < NBKT) ? bcnt[base + 2] : 0;
    int c3 = (base + 3 < NBKT) ? bcnt[base + 3] : 0;
    int ts = c0 + c1 + c2 + c3;
    sd[t] = ts;
    __syncthreads();
    for (int off = 1; off < 256; off <<= 1) {
        int v = (t >= off) ? sd[t - off] : 0;
        __syncthreads();
        sd[t] += v;
        __syncthreads();
    }
    int excl = sd[t] - ts;
    if (base + 0 < 783) bstart[base + 0] = excl;
    if (base + 1 < 783) bstart[base + 1] = excl + c0;
    if (base + 2 < 783) bstart[base + 2] = excl + c0 + c1;
    if (base + 3 < 783) bstart[base + 3] = excl + c0 + c1 + c2;
    if (t == 0) rowstart[NN] = NE;
}

// ---------------- fused per-bucket fill (flattened edge index) --------------
__global__ __launch_bounds__(256) void k_fillfused(
    const unsigned* __restrict__ edgebuf, const int* __restrict__ runstart,
    const int* __restrict__ bstart,
    int* __restrict__ rowstart, float* __restrict__ dis, int* __restrict__ colidx)
{
    __shared__ int rl[NW];
    __shared__ int pfx[NW];
    __shared__ int basea[NW];
    __shared__ unsigned short map[MAPCAP];
    __shared__ int lcnt[BKT_W];
    __shared__ int lcur[BKT_W];
    __shared__ int sd[256];
    const int b = blockIdx.x;
    const int t = threadIdx.x;
    const int bs = bstart[b];
    const int total = bstart[b + 1] - bs;

    for (int w = t; w < NW; w += 256) {
        int s0 = runstart[w * RSTR + b];
        int s1 = runstart[w * RSTR + b + 1];
        basea[w] = s0;
        rl[w] = s1 - s0;
    }
    if (t < BKT_W) lcnt[t] = 0;
    __syncthreads();
    {
        int w0 = t * 2;
        int c0 = (w0 < NW) ? rl[w0] : 0;
        int c1 = (w0 + 1 < NW) ? rl[w0 + 1] : 0;
        int ts = c0 + c1;
        sd[t] = ts;
        __syncthreads();
        for (int off = 1; off < 256; off <<= 1) {
            int v = (t >= off) ? sd[t - off] : 0;
            __syncthreads();
            sd[t] += v;
            __syncthreads();
        }
        int excl = sd[t] - ts;
        if (w0 < NW)     pfx[w0]     = excl;
        if (w0 + 1 < NW) pfx[w0 + 1] = excl + c0;
    }
    __syncthreads();
    for (int w = t; w < NW; w += 256) {
        int p = pfx[w], len = rl[w];
        basea[w] = w * CH + basea[w] - p;
        for (int i = 0; i < len; ++i) map[p + i] = (unsigned short)w;
    }
    __syncthreads();
    for (int j = t; j < total; j += 256) {
        unsigned p = edgebuf[basea[map[j]] + j];
        atomicAdd(&lcnt[p & (BKT_W - 1)], 1);
    }
    __syncthreads();
    if (t < BKT_W) lcur[t] = lcnt[t];
    __syncthreads();
    for (int off = 1; off < BKT_W; off <<= 1) {
        int v = (t < BKT_W && t >= off) ? lcur[t - off] : 0;
        __syncthreads();
        if (t < BKT_W) lcur[t] += v;
        __syncthreads();
    }
    if (t < BKT_W) {
        int excl = lcur[t] - lcnt[t];
        int node = b * BKT_W + t;
        if (node < NN) {
            rowstart[node] = bs + excl;
            dis[node] = rsqrtf((float)lcnt[t] + 1.0f);
        }
        lcur[t] = bs + excl;
    }
    __syncthreads();
    for (int j = t; j < total; j += 256) {
        unsigned p = edgebuf[basea[map[j]] + j];
        int pos = atomicAdd(&lcur[p & (BKT_W - 1)], 1);
        colidx[pos] = (int)(p >> BKT_SH);
    }
}

// ---------------- GEMM1: xs1 = bf16x2{(x @ W1) * dis}, 64B/node row ---------
__global__ __launch_bounds__(256) void k_gemm1(
    const float* __restrict__ x, const float* __restrict__ W1,
    const float* __restrict__ dis,
    unsigned* __restrict__ xs1)
{
    __shared__ float xls[128 * 33];
    __shared__ float wls[32 * 32];
    const int t = threadIdx.x;
    const int tc = t & 7;
    const int tr = t >> 3;
    const int base = blockIdx.x * 128;

    float a[4][4] = {};

    for (int k0 = 0; k0 < NF; k0 += 32) {
        {
            int i = t * 4;
            int kk = i >> 5, c = i & 31;
            *(float4*)&wls[kk * 32 + c] = *(const float4*)&W1[(k0 + kk) * C1 + c];
        }
        #pragma unroll
        for (int r = 0; r < 4; ++r) {
            int n = (t >> 3) + r * 32;
            int j = (t & 7) * 4;
            int node = base + n;
            float4 v = make_float4(0.f, 0.f, 0.f, 0.f);
            if (node < NN) v = *(const float4*)&x[(long long)node * NF + k0 + j];
            xls[n * 33 + j + 0] = v.x;
            xls[n * 33 + j + 1] = v.y;
            xls[n * 33 + j + 2] = v.z;
            xls[n * 33 + j + 3] = v.w;
        }
        __syncthreads();
        #pragma unroll 8
        for (int kk = 0; kk < 32; ++kk) {
            float4 w = *(const float4*)&wls[kk * 32 + tc * 4];
            #pragma unroll
            for (int i = 0; i < 4; ++i) {
                float xv = xls[(tr * 4 + i) * 33 + kk];
                a[i][0] = fmaf(xv, w.x, a[i][0]);
                a[i][1] = fmaf(xv, w.y, a[i][1]);
                a[i][2] = fmaf(xv, w.z, a[i][2]);
                a[i][3] = fmaf(xv, w.w, a[i][3]);
            }
        }
        __syncthreads();
    }
    #pragma unroll
    for (int i = 0; i < 4; ++i) {
        int node = base + tr * 4 + i;
        if (node < NN) {
            float dv = dis[node];
            uint2 o;
            o.x = pack_bf2(a[i][0] * dv, a[i][1] * dv);
            o.y = pack_bf2(a[i][2] * dv, a[i][3] * dv);
            *(uint2*)&xs1[node * 16 + tc * 2] = o;
        }
    }
}

// ---------------- gather layer1 (merged halves) + fused GEMM2 epilogue ------
// 8 lanes/node: each lane owns cols 4l..4l+3 (one uint2 of the 64B node row).
// One CSR pass gathers all 32 cols; h-row staged in LDS; GEMM2 + bf16 pack fused.
__global__ __launch_bounds__(256) void k_gather1(
    const unsigned* __restrict__ xs1, const int* __restrict__ colidx,
    const int* __restrict__ rowstart, const float* __restrict__ dis,
    const float* __restrict__ b1, const float* __restrict__ W2,
    unsigned* __restrict__ xs2b)
{
    __shared__ float w2s[C1 * C2];
    __shared__ float hrow[32 * 33];
    const int t = threadIdx.x;
    if (t < 128) *(float4*)&w2s[t * 4] = *(const float4*)&W2[t * 4];
    const int l = t & 7;
    const int n = t >> 3;
    const int v = blockIdx.x * 32 + n;   // NN = 100000 = 3125*32 exactly

    const int start = rowstart[v];
    const int num = rowstart[v + 1] - start;
    const int* __restrict__ cp = &colidx[start];
    uint2 u = *(const uint2*)&xs1[v * 16 + l * 2];   // self loop
    float4 a0 = make_float4(0.f, 0.f, 0.f, 0.f);
    acc4(a0, u);
    float4 a1 = make_float4(0.f, 0.f, 0.f, 0.f), a2 = a1, a3 = a1;
    int i = 0;
    for (; i + 8 <= num; i += 8) {
        int s0 = cp[i], s1 = cp[i+1], s2 = cp[i+2], s3 = cp[i+3];
        int s4 = cp[i+4], s5 = cp[i+5], s6 = cp[i+6], s7 = cp[i+7];
        uint2 q0 = *(const uint2*)&xs1[s0 * 16 + l * 2];
        uint2 q1 = *(const uint2*)&xs1[s1 * 16 + l * 2];
        uint2 q2 = *(const uint2*)&xs1[s2 * 16 + l * 2];
        uint2 q3 = *(const uint2*)&xs1[s3 * 16 + l * 2];
        uint2 q4 = *(const uint2*)&xs1[s4 * 16 + l * 2];
        uint2 q5 = *(const uint2*)&xs1[s5 * 16 + l * 2];
        uint2 q6 = *(const uint2*)&xs1[s6 * 16 + l * 2];
        uint2 q7 = *(const uint2*)&xs1[s7 * 16 + l * 2];
        acc4(a0, q0); acc4(a1, q1); acc4(a2, q2); acc4(a3, q3);
        acc4(a0, q4); acc4(a1, q5); acc4(a2, q6); acc4(a3, q7);
    }
    for (; i < num; ++i) {
        uint2 q = *(const uint2*)&xs1[cp[i] * 16 + l * 2];
        acc4(a0, q);
    }
    float ax = (a0.x + a1.x) + (a2.x + a3.x);
    float ay = (a0.y + a1.y) + (a2.y + a3.y);
    float az = (a0.z + a1.z) + (a2.z + a3.z);
    float aw = (a0.w + a1.w) + (a2.w + a3.w);
    const float dv = dis[v];

    hrow[n * 33 + l * 4 + 0] = fmaxf(fmaf(ax, dv, b1[l * 4 + 0]), 0.f);
    hrow[n * 33 + l * 4 + 1] = fmaxf(fmaf(ay, dv, b1[l * 4 + 1]), 0.f);
    hrow[n * 33 + l * 4 + 2] = fmaxf(fmaf(az, dv, b1[l * 4 + 2]), 0.f);
    hrow[n * 33 + l * 4 + 3] = fmaxf(fmaf(aw, dv, b1[l * 4 + 3]), 0.f);
    __syncthreads();

    // GEMM2 epilogue: lane l computes output cols 2l, 2l+1
    const float* hr = &hrow[n * 33];
    float s0 = 0.f, s1 = 0.f;
    #pragma unroll
    for (int k = 0; k < 32; ++k) {
        float hv = hr[k];
        s0 = fmaf(hv, w2s[k * C2 + 2 * l + 0], s0);
        s1 = fmaf(hv, w2s[k * C2 + 2 * l + 1], s1);
    }
    xs2b[v * 8 + l] = pack_bf2(s0 * dv, s1 * dv);
}

// ---------------- gather layer2 + fused mean-pool (no bias; folded in final)-
__global__ __launch_bounds__(256) void k_gather2(
    const unsigned* __restrict__ xs2b, const int* __restrict__ colidx,
    const int* __restrict__ rowstart, const float* __restrict__ dis,
    const int* __restrict__ batch,
    float* __restrict__ pool, float* __restrict__ cntf)
{
    __shared__ float psum[NG * C2];
    __shared__ float cs[NG];
    const int t = threadIdx.x;
    for (int i = t; i < NG * C2; i += 256) psum[i] = 0.f;
    if (t < NG) cs[t] = 0.f;
    __syncthreads();

    const int l = t & 3;
    const int n = t >> 2;
    const int v = blockIdx.x * 64 + n;
    if (v < NN) {
        const int start = rowstart[v];
        const int num = rowstart[v + 1] - start;
        const int* __restrict__ cp = &colidx[start];
        uint2 u = *(const uint2*)&xs2b[v * 8 + l * 2];   // self loop
        float4 a0 = make_float4(0.f, 0.f, 0.f, 0.f);
        acc4(a0, u);
        float4 a1 = make_float4(0.f, 0.f, 0.f, 0.f), a2 = a1, a3 = a1;
        int i = 0;
        for (; i + 8 <= num; i += 8) {
            int s0 = cp[i], s1 = cp[i+1], s2 = cp[i+2], s3 = cp[i+3];
            int s4 = cp[i+4], s5 = cp[i+5], s6 = cp[i+6], s7 = cp[i+7];
            uint2 q0 = *(const uint2*)&xs2b[s0 * 8 + l * 2];
            uint2 q1 = *(const uint2*)&xs2b[s1 * 8 + l * 2];
            uint2 q2 = *(const uint2*)&xs2b[s2 * 8 + l * 2];
            uint2 q3 = *(const uint2*)&xs2b[s3 * 8 + l * 2];
            uint2 q4 = *(const uint2*)&xs2b[s4 * 8 + l * 2];
            uint2 q5 = *(const uint2*)&xs2b[s5 * 8 + l * 2];
            uint2 q6 = *(const uint2*)&xs2b[s6 * 8 + l * 2];
            uint2 q7 = *(const uint2*)&xs2b[s7 * 8 + l * 2];
            acc4(a0, q0); acc4(a1, q1); acc4(a2, q2); acc4(a3, q3);
            acc4(a0, q4); acc4(a1, q5); acc4(a2, q6); acc4(a3, q7);
        }
        for (; i < num; ++i) {
            uint2 q = *(const uint2*)&xs2b[cp[i] * 8 + l * 2];
            acc4(a0, q);
        }
        float ax = (a0.x + a1.x) + (a2.x + a3.x);
        float ay = (a0.y + a1.y) + (a2.y + a3.y);
        float az = (a0.z + a1.z) + (a2.z + a3.z);
        float aw = (a0.w + a1.w) + (a2.w + a3.w);
        float dv = dis[v];
        int g = batch[v];
        atomicAdd(&psum[g * C2 + l * 4 + 0], ax * dv);
        atomicAdd(&psum[g * C2 + l * 4 + 1], ay * dv);
        atomicAdd(&psum[g * C2 + l * 4 + 2], az * dv);
        atomicAdd(&psum[g * C2 + l * 4 + 3], aw * dv);
        if (l == 0) atomicAdd(&cs[g], 1.0f);
    }
    __syncthreads();
    for (int i = t; i < NG * C2; i += 256)
        if (psum[i] != 0.f) atomicAdd(&pool[i], psum[i]);
    if (t < NG && cs[t] != 0.f) atomicAdd(&cntf[t], cs[t]);
}

// ---------------- final: out[g] = (pool/cnt + b2) @ lw + lb -----------------
__global__ void k_final(const float* __restrict__ pool, const float* __restrict__ cntf,
                        const float* __restrict__ b2,
                        const float* __restrict__ lw, const float* __restrict__ lb,
                        float* __restrict__ out)
{
    int g = threadIdx.x;
    if (g < NG) {
        float c = fmaxf(cntf[g], 1.0f);
        float inv = 1.0f / c;
        float s = lb[0];
        #pragma unroll
        for (int k = 0; k < C2; ++k) {
            s = fmaf(b2[k], lw[k], s);                    // bias fold
            s = fmaf(pool[g * C2 + k] * inv, lw[k], s);
        }
        out[g] = s;
    }
}

extern "C" void kernel_launch(void* const* d_in, const int* in_sizes, int n_in,
                              void* d_out, int out_size, void* d_ws, size_t ws_size,
                              hipStream_t stream) {
    const float* x     = (const float*)d_in[0];
    const int*   ei    = (const int*)d_in[1];
    const int*   batch = (const int*)d_in[2];
    const float* W1    = (const float*)d_in[3];
    const float* b1    = (const float*)d_in[4];
    const float* W2    = (const float*)d_in[5];
    const float* b2    = (const float*)d_in[6];
    const float* lw    = (const float*)d_in[7];
    const float* lb    = (const float*)d_in[8];
    float* out = (float*)d_out;

    float*    wsf = (float*)d_ws;
    int*      wsi = (int*)d_ws;
    unsigned* wsu = (unsigned*)d_ws;

    int*      bcnt     = wsi + OFF_BCNT;
    int*      bstart   = wsi + OFF_BST;
    int*      runstart = wsi + OFF_RUN;
    int*      rowstart = wsi + OFF_ROW;
    float*    dis      = wsf + OFF_DIS;
    float*    pool     = wsf + OFF_POOL;
    float*    cntf     = wsf + OFF_CNTF;
    unsigned* edgebuf  = wsu + OFF_EDG;
    unsigned* xs1      = wsu + OFF_XS1;    // aliases edgebuf (dead after fillfused)
    unsigned* xs2b     = wsu + OFF_XS2B;
    int*      colidx   = wsi + OFF_COL;

    const int* S = ei;            // edge_index[0] (src)
    const int* D = ei + NE;       // edge_index[1] (dst)

    hipMemsetAsync(bcnt, 0, 1024 * sizeof(int), stream);
    hipMemsetAsync(pool, 0, (NG * C2 + NG) * sizeof(float), stream);

    k_part       <<<NW, 512, 0, stream>>>(S, D, edgebuf, runstart, bcnt);
    k_bscan      <<<1, 256, 0, stream>>>(bcnt, bstart, rowstart);
    k_fillfused  <<<NBKT, 256, 0, stream>>>(edgebuf, runstart, bstart, rowstart, dis, colidx);
    k_gemm1      <<<(NN + 127) / 128, 256, 0, stream>>>(x, W1, dis, xs1);
    k_gather1    <<<NN / 32, 256, 0, stream>>>(xs1, colidx, rowstart, dis, b1, W2, xs2b);
    k_gather2    <<<(NN + 63) / 64, 256, 0, stream>>>(xs2b, colidx, rowstart, dis, batch, pool, cntf);
    k_final      <<<1, 64, 0, stream>>>(pool, cntf, b2, lw, lb, out);
}

// Round 2
// 251.194 us; speedup vs baseline: 1.1363x; 1.0240x over previous
//
#include <hip/hip_runtime.h>

#define NN 100000
#define NE 3200000
#define NF 128
#define C1 32
#define C2 16
#define NG 64
#define BKT_SH 7
#define BKT_W  128
#define NBKT   782          // ceil(NN/128)
#define CH     8192         // edges per partition chunk
#define NW     391          // ceil(NE/CH)
#define RSTR   784          // runstart row stride (783 used)
#define MAPCAP 6400         // per-bucket flattened-edge capacity (mean 4092, sd 64)

// ---- workspace layout (4-byte element offsets) ----
// bcnt/pool/cntf adjacent -> ONE memset covers all zeroed state.
#define OFF_BCNT  0            // 1024 ints (782 used)
#define OFF_POOL  1024         // NG*C2 = 1024 floats
#define OFF_CNTF  2048         // NG floats (pad to 2304)
#define OFF_RUN   2304         // NW*RSTR = 306,544 ints -> 308,848
#define OFF_ROW   308848       // NN+1 ints -> 408,849 (pad to 408,864)
#define OFF_DIS   408864       // NN floats -> 508,864
#define OFF_EDG   508864       // NE uints (dead after fillfused); 16B aligned
#define OFF_XS1   OFF_EDG                  // NN*16 uints bf16x2 cols 0..31 (aliases edgebuf)
#define OFF_XS2B  (OFF_EDG + NE)           // NN*8 uints bf16x2; 16B aligned
#define OFF_COL   (OFF_XS2B + NN*8)        // NE ints CSR col indices

// ---- bf16x2 pack/unpack (RNE) ----
__device__ __forceinline__ unsigned pack_bf2(float a, float b) {
    unsigned ua = __float_as_uint(a);
    unsigned ub = __float_as_uint(b);
    ua = (ua + 0x7fffu + ((ua >> 16) & 1u)) >> 16;
    ub = (ub + 0x7fffu + ((ub >> 16) & 1u)) & 0xffff0000u;
    return ua | ub;   // lo = a, hi = b
}
__device__ __forceinline__ float2 unpack_bf2(unsigned u) {
    return make_float2(__uint_as_float(u << 16), __uint_as_float(u & 0xffff0000u));
}
__device__ __forceinline__ void accum8(float* a, uint4 q) {
    float2 f0 = unpack_bf2(q.x), f1 = unpack_bf2(q.y);
    float2 f2 = unpack_bf2(q.z), f3 = unpack_bf2(q.w);
    a[0] += f0.x; a[1] += f0.y; a[2] += f1.x; a[3] += f1.y;
    a[4] += f2.x; a[5] += f2.y; a[6] += f3.x; a[7] += f3.y;
}

// ---------------- k_part: per-chunk counting sort by bucket -----------------
// 512 threads; int4-vectorized edge IO; wave-shuffle scan (1 barrier).
__global__ __launch_bounds__(512) void k_part(
    const int* __restrict__ S, const int* __restrict__ D,
    unsigned* __restrict__ edgebuf, int* __restrict__ runstart,
    int* __restrict__ bcnt)
{
    __shared__ int lhist[1024];
    __shared__ int lstart[1024];
    __shared__ int lcur[NBKT];
    __shared__ int wsum[8];
    __shared__ unsigned lsort[CH];
    const int w = blockIdx.x;
    const int t = threadIdx.x;
    const int e0 = w * CH;
    const int n = min(CH, NE - e0);     // 8192 or 5120 (last); both %4 == 0
    const int n4 = n >> 2;
    const int4* __restrict__ S4 = (const int4*)(S + e0);
    const int4* __restrict__ D4 = (const int4*)(D + e0);

    for (int i = t; i < 1024; i += 512) lhist[i] = 0;
    __syncthreads();
    for (int i = t; i < n4; i += 512) {
        int4 d = D4[i];
        atomicAdd(&lhist[(unsigned)d.x >> BKT_SH], 1);
        atomicAdd(&lhist[(unsigned)d.y >> BKT_SH], 1);
        atomicAdd(&lhist[(unsigned)d.z >> BKT_SH], 1);
        atomicAdd(&lhist[(unsigned)d.w >> BKT_SH], 1);
    }
    __syncthreads();
    for (int i = t; i < NBKT; i += 512) atomicAdd(&bcnt[i], lhist[i]);

    // exclusive scan of 1024 hist entries: 2 per thread, wave-shuffle scan
    int c0 = lhist[t * 2 + 0], c1 = lhist[t * 2 + 1];
    int ts = c0 + c1;
    const int lane = t & 63, wv = t >> 6;
    int sc = ts;
    #pragma unroll
    for (int off = 1; off < 64; off <<= 1) {
        int v = __shfl_up(sc, off, 64);
        if (lane >= off) sc += v;
    }
    if (lane == 63) wsum[wv] = sc;
    __syncthreads();
    int wo = 0;
    #pragma unroll
    for (int i = 0; i < 8; ++i) wo += (i < wv) ? wsum[i] : 0;
    int excl = sc - ts + wo;
    lstart[t * 2 + 0] = excl;
    lstart[t * 2 + 1] = excl + c0;
    __syncthreads();

    for (int i = t; i < 783; i += 512) runstart[w * RSTR + i] = lstart[i];
    for (int i = t; i < NBKT; i += 512) lcur[i] = lstart[i];
    __syncthreads();
    for (int i = t; i < n4; i += 512) {
        int4 s = S4[i];
        int4 d = D4[i];
        { int p = atomicAdd(&lcur[(unsigned)d.x >> BKT_SH], 1);
          lsort[p] = ((unsigned)s.x << BKT_SH) | ((unsigned)d.x & (BKT_W - 1)); }
        { int p = atomicAdd(&lcur[(unsigned)d.y >> BKT_SH], 1);
          lsort[p] = ((unsigned)s.y << BKT_SH) | ((unsigned)d.y & (BKT_W - 1)); }
        { int p = atomicAdd(&lcur[(unsigned)d.z >> BKT_SH], 1);
          lsort[p] = ((unsigned)s.z << BKT_SH) | ((unsigned)d.z & (BKT_W - 1)); }
        { int p = atomicAdd(&lcur[(unsigned)d.w >> BKT_SH], 1);
          lsort[p] = ((unsigned)s.w << BKT_SH) | ((unsigned)d.w & (BKT_W - 1)); }
    }
    __syncthreads();
    {
        uint4* __restrict__ eb4 = (uint4*)(edgebuf + e0);
        const uint4* __restrict__ ls4 = (const uint4*)lsort;
        for (int i = t; i < n4; i += 512) eb4[i] = ls4[i];
    }
}

// ---------------- fused per-bucket fill (bscan folded in) -------------------
__global__ __launch_bounds__(256) void k_fillfused(
    const unsigned* __restrict__ edgebuf, const int* __restrict__ runstart,
    const int* __restrict__ bcnt,
    int* __restrict__ rowstart, float* __restrict__ dis, int* __restrict__ colidx)
{
    __shared__ int rl[NW];
    __shared__ int pfx[NW];
    __shared__ int basea[NW];
    __shared__ unsigned short map[MAPCAP];
    __shared__ int lcnt[BKT_W];
    __shared__ int lcur[BKT_W];
    __shared__ int wsum[4];
    __shared__ int hs1;
    const int b = blockIdx.x;
    const int t = threadIdx.x;
    const int lane = t & 63, wv = t >> 6;

    // --- bs = sum(bcnt[0..b)) : strided + full-wave xor reduce
    int accp = 0;
    for (int i = t; i < b; i += 256) accp += bcnt[i];
    #pragma unroll
    for (int off = 1; off < 64; off <<= 1) accp += __shfl_xor(accp, off, 64);
    if (lane == 0) wsum[wv] = accp;

    for (int w = t; w < NW; w += 256) {
        int s0 = runstart[w * RSTR + b];
        int s1 = runstart[w * RSTR + b + 1];
        basea[w] = s0;
        rl[w] = s1 - s0;
    }
    if (t < BKT_W) lcnt[t] = 0;
    __syncthreads();
    const int bs = wsum[0] + wsum[1] + wsum[2] + wsum[3];

    // --- scan rl (391 entries, 2/thread, wave-shuffle)
    int w0 = t * 2;
    int c0 = (w0 < NW) ? rl[w0] : 0;
    int c1 = (w0 + 1 < NW) ? rl[w0 + 1] : 0;
    int ts = c0 + c1;
    int sc = ts;
    #pragma unroll
    for (int off = 1; off < 64; off <<= 1) {
        int v = __shfl_up(sc, off, 64);
        if (lane >= off) sc += v;
    }
    __syncthreads();                       // all bs-reads done before wsum reuse
    if (lane == 63) wsum[wv] = sc;
    __syncthreads();
    int wo = 0;
    #pragma unroll
    for (int i = 0; i < 4; ++i) wo += (i < wv) ? wsum[i] : 0;
    const int total = wsum[0] + wsum[1] + wsum[2] + wsum[3];
    int excl0 = sc - ts + wo;
    if (w0 < NW)     pfx[w0]     = excl0;
    if (w0 + 1 < NW) pfx[w0 + 1] = excl0 + c0;
    __syncthreads();

    for (int w = t; w < NW; w += 256) {
        int p = pfx[w], len = rl[w];
        basea[w] = w * CH + basea[w] - p;
        for (int i = 0; i < len; ++i) map[p + i] = (unsigned short)w;
    }
    __syncthreads();
    for (int j = t; j < total; j += 256) {
        unsigned p = edgebuf[basea[map[j]] + j];
        atomicAdd(&lcnt[p & (BKT_W - 1)], 1);
    }
    __syncthreads();

    // --- 128-wide scan of lcnt: 2-wave shuffle scan, 1 barrier
    int myc = 0, sc2 = 0;
    if (t < BKT_W) {
        myc = lcnt[t];
        sc2 = myc;
        #pragma unroll
        for (int off = 1; off < 64; off <<= 1) {
            int v = __shfl_up(sc2, off, 64);
            if (lane >= off) sc2 += v;
        }
        if (t == 63) hs1 = sc2;
    }
    __syncthreads();
    if (t < BKT_W) {
        int excl = sc2 - myc + ((t >= 64) ? hs1 : 0);
        int node = b * BKT_W + t;
        if (node < NN) {
            rowstart[node] = bs + excl;
            dis[node] = rsqrtf((float)myc + 1.0f);
        }
        lcur[t] = bs + excl;
    }
    if (b == 0 && t == 0) rowstart[NN] = NE;
    __syncthreads();
    for (int j = t; j < total; j += 256) {
        unsigned p = edgebuf[basea[map[j]] + j];
        int pos = atomicAdd(&lcur[p & (BKT_W - 1)], 1);
        colidx[pos] = (int)(p >> BKT_SH);
    }
}

// ---------------- GEMM1: xs1 = bf16x2{(x @ W1) * dis}, 64B/node row ---------
__global__ __launch_bounds__(256) void k_gemm1(
    const float* __restrict__ x, const float* __restrict__ W1,
    const float* __restrict__ dis,
    unsigned* __restrict__ xs1)
{
    __shared__ float xls[128 * 33];
    __shared__ float wls[32 * 32];
    const int t = threadIdx.x;
    const int tc = t & 7;
    const int tr = t >> 3;
    const int base = blockIdx.x * 128;

    float a[4][4] = {};

    for (int k0 = 0; k0 < NF; k0 += 32) {
        {
            int i = t * 4;
            int kk = i >> 5, c = i & 31;
            *(float4*)&wls[kk * 32 + c] = *(const float4*)&W1[(k0 + kk) * C1 + c];
        }
        #pragma unroll
        for (int r = 0; r < 4; ++r) {
            int n = (t >> 3) + r * 32;
            int j = (t & 7) * 4;
            int node = base + n;
            float4 v = make_float4(0.f, 0.f, 0.f, 0.f);
            if (node < NN) v = *(const float4*)&x[(long long)node * NF + k0 + j];
            xls[n * 33 + j + 0] = v.x;
            xls[n * 33 + j + 1] = v.y;
            xls[n * 33 + j + 2] = v.z;
            xls[n * 33 + j + 3] = v.w;
        }
        __syncthreads();
        #pragma unroll 8
        for (int kk = 0; kk < 32; ++kk) {
            float4 w = *(const float4*)&wls[kk * 32 + tc * 4];
            #pragma unroll
            for (int i = 0; i < 4; ++i) {
                float xv = xls[(tr * 4 + i) * 33 + kk];
                a[i][0] = fmaf(xv, w.x, a[i][0]);
                a[i][1] = fmaf(xv, w.y, a[i][1]);
                a[i][2] = fmaf(xv, w.z, a[i][2]);
                a[i][3] = fmaf(xv, w.w, a[i][3]);
            }
        }
        __syncthreads();
    }
    #pragma unroll
    for (int i = 0; i < 4; ++i) {
        int node = base + tr * 4 + i;
        if (node < NN) {
            float dv = dis[node];
            uint2 o;
            o.x = pack_bf2(a[i][0] * dv, a[i][1] * dv);
            o.y = pack_bf2(a[i][2] * dv, a[i][3] * dv);
            *(uint2*)&xs1[node * 16 + tc * 2] = o;
        }
    }
}

// ---------------- gather layer1 + fused GEMM2 epilogue ----------------------
// 4 lanes/node, uint4 (16B) loads: half the load instrs of 8-lane uint2,
// same bytes, 2x in-flight bytes with 8-edge unroll.
__global__ __launch_bounds__(256) void k_gather1(
    const unsigned* __restrict__ xs1, const int* __restrict__ colidx,
    const int* __restrict__ rowstart, const float* __restrict__ dis,
    const float* __restrict__ b1, const float* __restrict__ W2,
    unsigned* __restrict__ xs2b)
{
    __shared__ float w2s[C1 * C2];
    __shared__ float hrow[64 * 33];
    const int t = threadIdx.x;
    if (t < 128) *(float4*)&w2s[t * 4] = *(const float4*)&W2[t * 4];
    const int l = t & 3;
    const int n = t >> 2;                 // 0..63
    const int v = blockIdx.x * 64 + n;
    const bool valid = v < NN;

    float a0[8] = {}, a1[8] = {};
    float dv = 0.f;
    if (valid) {
        const int start = rowstart[v];
        const int num = rowstart[v + 1] - start;
        const int* __restrict__ cp = &colidx[start];
        const uint4* __restrict__ tb = (const uint4*)xs1;   // row v = tb[v*4 + l]
        accum8(a0, tb[v * 4 + l]);                          // self loop
        int i = 0;
        for (; i + 8 <= num; i += 8) {
            int s0 = cp[i],   s1 = cp[i+1], s2 = cp[i+2], s3 = cp[i+3];
            int s4 = cp[i+4], s5 = cp[i+5], s6 = cp[i+6], s7 = cp[i+7];
            uint4 q0 = tb[s0 * 4 + l];
            uint4 q1 = tb[s1 * 4 + l];
            uint4 q2 = tb[s2 * 4 + l];
            uint4 q3 = tb[s3 * 4 + l];
            uint4 q4 = tb[s4 * 4 + l];
            uint4 q5 = tb[s5 * 4 + l];
            uint4 q6 = tb[s6 * 4 + l];
            uint4 q7 = tb[s7 * 4 + l];
            accum8(a0, q0); accum8(a1, q1); accum8(a0, q2); accum8(a1, q3);
            accum8(a0, q4); accum8(a1, q5); accum8(a0, q6); accum8(a1, q7);
        }
        for (; i < num; ++i) accum8(a0, tb[cp[i] * 4 + l]);
        dv = dis[v];
        #pragma unroll
        for (int j = 0; j < 8; ++j) {
            float h = fmaxf(fmaf(a0[j] + a1[j], dv, b1[l * 8 + j]), 0.f);
            hrow[n * 33 + l * 8 + j] = h;
        }
    }
    __syncthreads();
    if (valid) {
        const float* hr = &hrow[n * 33];
        float s0 = 0.f, s1 = 0.f, s2 = 0.f, s3 = 0.f;
        #pragma unroll
        for (int k = 0; k < 32; ++k) {
            float hv = hr[k];
            s0 = fmaf(hv, w2s[k * C2 + l * 4 + 0], s0);
            s1 = fmaf(hv, w2s[k * C2 + l * 4 + 1], s1);
            s2 = fmaf(hv, w2s[k * C2 + l * 4 + 2], s2);
            s3 = fmaf(hv, w2s[k * C2 + l * 4 + 3], s3);
        }
        uint2 o;
        o.x = pack_bf2(s0 * dv, s1 * dv);
        o.y = pack_bf2(s2 * dv, s3 * dv);
        *(uint2*)&xs2b[v * 8 + l * 2] = o;
    }
}

// ---------------- gather layer2 + fused mean-pool ---------------------------
// 2 lanes/node, uint4 loads. Wave-uniform graph-id fast path: butterfly
// reduce across the wave's 32 nodes -> 16 LDS atomics/wave instead of ~512
// same-address-serialized ones (batch is sorted, so uniform is the norm).
__global__ __launch_bounds__(256) void k_gather2(
    const unsigned* __restrict__ xs2b, const int* __restrict__ colidx,
    const int* __restrict__ rowstart, const float* __restrict__ dis,
    const int* __restrict__ batch,
    float* __restrict__ pool, float* __restrict__ cntf)
{
    __shared__ float psum[NG * C2];
    __shared__ float cs[NG];
    const int t = threadIdx.x;
    for (int i = t; i < NG * C2; i += 256) psum[i] = 0.f;
    if (t < NG) cs[t] = 0.f;
    __syncthreads();

    const int l = t & 1;
    const int n = t >> 1;                 // 0..127
    const int v = blockIdx.x * 128 + n;
    const bool valid = v < NN;
    const int lane = t & 63;

    float r[8] = {};
    int g = 0;
    if (valid) {
        const int start = rowstart[v];
        const int num = rowstart[v + 1] - start;
        const int* __restrict__ cp = &colidx[start];
        const uint4* __restrict__ tb = (const uint4*)xs2b;  // row v = tb[v*2 + l]
        float a0[8] = {}, a1[8] = {};
        accum8(a0, tb[v * 2 + l]);                          // self loop
        int i = 0;
        for (; i + 8 <= num; i += 8) {
            int s0 = cp[i],   s1 = cp[i+1], s2 = cp[i+2], s3 = cp[i+3];
            int s4 = cp[i+4], s5 = cp[i+5], s6 = cp[i+6], s7 = cp[i+7];
            uint4 q0 = tb[s0 * 2 + l];
            uint4 q1 = tb[s1 * 2 + l];
            uint4 q2 = tb[s2 * 2 + l];
            uint4 q3 = tb[s3 * 2 + l];
            uint4 q4 = tb[s4 * 2 + l];
            uint4 q5 = tb[s5 * 2 + l];
            uint4 q6 = tb[s6 * 2 + l];
            uint4 q7 = tb[s7 * 2 + l];
            accum8(a0, q0); accum8(a1, q1); accum8(a0, q2); accum8(a1, q3);
            accum8(a0, q4); accum8(a1, q5); accum8(a0, q6); accum8(a1, q7);
        }
        for (; i < num; ++i) accum8(a0, tb[cp[i] * 2 + l]);
        float dv = dis[v];
        g = batch[v];
        #pragma unroll
        for (int j = 0; j < 8; ++j) r[j] = (a0[j] + a1[j]) * dv;
    }

    int g0 = __shfl(g, 0, 64);
    bool uni = __all(!valid || g == g0);
    if (uni) {
        #pragma unroll
        for (int j = 0; j < 8; ++j) {
            float val = r[j];
            val += __shfl_xor(val, 2, 64);
            val += __shfl_xor(val, 4, 64);
            val += __shfl_xor(val, 8, 64);
            val += __shfl_xor(val, 16, 64);
            val += __shfl_xor(val, 32, 64);
            if (lane < 2) atomicAdd(&psum[g0 * C2 + lane * 8 + j], val);
        }
        unsigned long long mb = __ballot(valid && (l == 0));
        if (lane == 0 && mb) atomicAdd(&cs[g0], (float)__popcll(mb));
    } else {
        if (valid) {
            #pragma unroll
            for (int j = 0; j < 8; ++j)
                atomicAdd(&psum[g * C2 + l * 8 + j], r[j]);
            if (l == 0) atomicAdd(&cs[g], 1.0f);
        }
    }
    __syncthreads();
    for (int i = t; i < NG * C2; i += 256)
        if (psum[i] != 0.f) atomicAdd(&pool[i], psum[i]);
    if (t < NG && cs[t] != 0.f) atomicAdd(&cntf[t], cs[t]);
}

// ---------------- final: out[g] = (pool/cnt + b2) @ lw + lb -----------------
__global__ void k_final(const float* __restrict__ pool, const float* __restrict__ cntf,
                        const float* __restrict__ b2,
                        const float* __restrict__ lw, const float* __restrict__ lb,
                        float* __restrict__ out)
{
    int g = threadIdx.x;
    if (g < NG) {
        float c = fmaxf(cntf[g], 1.0f);
        float inv = 1.0f / c;
        float s = lb[0];
        #pragma unroll
        for (int k = 0; k < C2; ++k) {
            s = fmaf(b2[k], lw[k], s);                    // bias fold
            s = fmaf(pool[g * C2 + k] * inv, lw[k], s);
        }
        out[g] = s;
    }
}

extern "C" void kernel_launch(void* const* d_in, const int* in_sizes, int n_in,
                              void* d_out, int out_size, void* d_ws, size_t ws_size,
                              hipStream_t stream) {
    const float* x     = (const float*)d_in[0];
    const int*   ei    = (const int*)d_in[1];
    const int*   batch = (const int*)d_in[2];
    const float* W1    = (const float*)d_in[3];
    const float* b1    = (const float*)d_in[4];
    const float* W2    = (const float*)d_in[5];
    const float* b2    = (const float*)d_in[6];
    const float* lw    = (const float*)d_in[7];
    const float* lb    = (const float*)d_in[8];
    float* out = (float*)d_out;

    float*    wsf = (float*)d_ws;
    int*      wsi = (int*)d_ws;
    unsigned* wsu = (unsigned*)d_ws;

    int*      bcnt     = wsi + OFF_BCNT;
    float*    pool     = wsf + OFF_POOL;
    float*    cntf     = wsf + OFF_CNTF;
    int*      runstart = wsi + OFF_RUN;
    int*      rowstart = wsi + OFF_ROW;
    float*    dis      = wsf + OFF_DIS;
    unsigned* edgebuf  = wsu + OFF_EDG;
    unsigned* xs1      = wsu + OFF_XS1;    // aliases edgebuf (dead after fillfused)
    unsigned* xs2b     = wsu + OFF_XS2B;
    int*      colidx   = wsi + OFF_COL;

    const int* S = ei;            // edge_index[0] (src)
    const int* D = ei + NE;       // edge_index[1] (dst)

    hipMemsetAsync(wsi + OFF_BCNT, 0, 2304 * sizeof(int), stream);  // bcnt+pool+cntf

    k_part       <<<NW, 512, 0, stream>>>(S, D, edgebuf, runstart, bcnt);
    k_fillfused  <<<NBKT, 256, 0, stream>>>(edgebuf, runstart, bcnt, rowstart, dis, colidx);
    k_gemm1      <<<(NN + 127) / 128, 256, 0, stream>>>(x, W1, dis, xs1);
    k_gather1    <<<(NN + 63) / 64, 256, 0, stream>>>(xs1, colidx, rowstart, dis, b1, W2, xs2b);
    k_gather2    <<<(NN + 127) / 128, 256, 0, stream>>>(xs2b, colidx, rowstart, dis, batch, pool, cntf);
    k_final      <<<1, 64, 0, stream>>>(pool, cntf, b2, lw, lb, out);
}

// Round 3
// 243.680 us; speedup vs baseline: 1.1713x; 1.0308x over previous
//
#include <hip/hip_runtime.h>

#define NN 100000
#define NE 3200000
#define NF 128
#define C1 32
#define C2 16
#define NG 64
#define BKT_SH 7
#define BKT_W  128
#define NBKT   782          // ceil(NN/128)
#define CH     8192         // edges per partition chunk
#define NW     391          // ceil(NE/CH)
#define RSTR   784          // runstart row stride (783 used)
#define MAPCAP 6400         // per-bucket flattened-edge capacity (mean 4092, sd 64)

// ---- workspace layout (4-byte element offsets) ----
// bcnt/pool/cntf adjacent -> ONE memset covers all zeroed state.
#define OFF_BCNT  0            // 1024 ints (782 used)
#define OFF_POOL  1024         // NG*C2 = 1024 floats
#define OFF_CNTF  2048         // NG floats (pad to 2304)
#define OFF_RUN   2304         // NW*RSTR = 306,544 ints -> 308,848
#define OFF_ROW   308848       // NN+1 ints -> 408,849 (pad to 408,864)
#define OFF_DIS   408864       // NN floats -> 508,864
#define OFF_EDG   508864       // NE uints (dead after fillfused); 16B aligned
#define OFF_XS1   OFF_EDG                  // NN*16 uints bf16x2 cols 0..31 (aliases edgebuf)
#define OFF_XS2B  (OFF_EDG + NE)           // NN*8 uints bf16x2; 16B aligned
#define OFF_COL   (OFF_XS2B + NN*8)        // NE ints CSR col indices

// ---- bf16x2 pack/unpack (RNE) ----
__device__ __forceinline__ unsigned pack_bf2(float a, float b) {
    unsigned ua = __float_as_uint(a);
    unsigned ub = __float_as_uint(b);
    ua = (ua + 0x7fffu + ((ua >> 16) & 1u)) >> 16;
    ub = (ub + 0x7fffu + ((ub >> 16) & 1u)) & 0xffff0000u;
    return ua | ub;   // lo = a, hi = b
}
__device__ __forceinline__ float2 unpack_bf2(unsigned u) {
    return make_float2(__uint_as_float(u << 16), __uint_as_float(u & 0xffff0000u));
}
__device__ __forceinline__ void acc4(float4& a, uint2 q) {
    float2 f0 = unpack_bf2(q.x), f1 = unpack_bf2(q.y);
    a.x += f0.x; a.y += f0.y; a.z += f1.x; a.w += f1.y;
}

// ---------------- k_part: per-chunk counting sort by bucket -----------------
// 512 threads; int4-vectorized edge IO; wave-shuffle scan (1 barrier).
__global__ __launch_bounds__(512) void k_part(
    const int* __restrict__ S, const int* __restrict__ D,
    unsigned* __restrict__ edgebuf, int* __restrict__ runstart,
    int* __restrict__ bcnt)
{
    __shared__ int lhist[1024];
    __shared__ int lstart[1024];
    __shared__ int lcur[NBKT];
    __shared__ int wsum[8];
    __shared__ unsigned lsort[CH];
    const int w = blockIdx.x;
    const int t = threadIdx.x;
    const int e0 = w * CH;
    const int n = min(CH, NE - e0);     // 8192 or 5120 (last); both %4 == 0
    const int n4 = n >> 2;
    const int4* __restrict__ S4 = (const int4*)(S + e0);
    const int4* __restrict__ D4 = (const int4*)(D + e0);

    for (int i = t; i < 1024; i += 512) lhist[i] = 0;
    __syncthreads();
    for (int i = t; i < n4; i += 512) {
        int4 d = D4[i];
        atomicAdd(&lhist[(unsigned)d.x >> BKT_SH], 1);
        atomicAdd(&lhist[(unsigned)d.y >> BKT_SH], 1);
        atomicAdd(&lhist[(unsigned)d.z >> BKT_SH], 1);
        atomicAdd(&lhist[(unsigned)d.w >> BKT_SH], 1);
    }
    __syncthreads();
    for (int i = t; i < NBKT; i += 512) atomicAdd(&bcnt[i], lhist[i]);

    // exclusive scan of 1024 hist entries: 2 per thread, wave-shuffle scan
    int c0 = lhist[t * 2 + 0], c1 = lhist[t * 2 + 1];
    int ts = c0 + c1;
    const int lane = t & 63, wv = t >> 6;
    int sc = ts;
    #pragma unroll
    for (int off = 1; off < 64; off <<= 1) {
        int v = __shfl_up(sc, off, 64);
        if (lane >= off) sc += v;
    }
    if (lane == 63) wsum[wv] = sc;
    __syncthreads();
    int wo = 0;
    #pragma unroll
    for (int i = 0; i < 8; ++i) wo += (i < wv) ? wsum[i] : 0;
    int excl = sc - ts + wo;
    lstart[t * 2 + 0] = excl;
    lstart[t * 2 + 1] = excl + c0;
    __syncthreads();

    for (int i = t; i < 783; i += 512) runstart[w * RSTR + i] = lstart[i];
    for (int i = t; i < NBKT; i += 512) lcur[i] = lstart[i];
    __syncthreads();
    for (int i = t; i < n4; i += 512) {
        int4 s = S4[i];
        int4 d = D4[i];
        { int p = atomicAdd(&lcur[(unsigned)d.x >> BKT_SH], 1);
          lsort[p] = ((unsigned)s.x << BKT_SH) | ((unsigned)d.x & (BKT_W - 1)); }
        { int p = atomicAdd(&lcur[(unsigned)d.y >> BKT_SH], 1);
          lsort[p] = ((unsigned)s.y << BKT_SH) | ((unsigned)d.y & (BKT_W - 1)); }
        { int p = atomicAdd(&lcur[(unsigned)d.z >> BKT_SH], 1);
          lsort[p] = ((unsigned)s.z << BKT_SH) | ((unsigned)d.z & (BKT_W - 1)); }
        { int p = atomicAdd(&lcur[(unsigned)d.w >> BKT_SH], 1);
          lsort[p] = ((unsigned)s.w << BKT_SH) | ((unsigned)d.w & (BKT_W - 1)); }
    }
    __syncthreads();
    {
        uint4* __restrict__ eb4 = (uint4*)(edgebuf + e0);
        const uint4* __restrict__ ls4 = (const uint4*)lsort;
        for (int i = t; i < n4; i += 512) eb4[i] = ls4[i];
    }
}

// ---------------- fused per-bucket fill (bscan folded in) -------------------
__global__ __launch_bounds__(256) void k_fillfused(
    const unsigned* __restrict__ edgebuf, const int* __restrict__ runstart,
    const int* __restrict__ bcnt,
    int* __restrict__ rowstart, float* __restrict__ dis, int* __restrict__ colidx)
{
    __shared__ int rl[NW];
    __shared__ int pfx[NW];
    __shared__ int basea[NW];
    __shared__ unsigned short map[MAPCAP];
    __shared__ int lcnt[BKT_W];
    __shared__ int lcur[BKT_W];
    __shared__ int wsum[4];
    __shared__ int hs1;
    const int b = blockIdx.x;
    const int t = threadIdx.x;
    const int lane = t & 63, wv = t >> 6;

    // --- bs = sum(bcnt[0..b)) : strided + full-wave xor reduce
    int accp = 0;
    for (int i = t; i < b; i += 256) accp += bcnt[i];
    #pragma unroll
    for (int off = 1; off < 64; off <<= 1) accp += __shfl_xor(accp, off, 64);
    if (lane == 0) wsum[wv] = accp;

    for (int w = t; w < NW; w += 256) {
        int s0 = runstart[w * RSTR + b];
        int s1 = runstart[w * RSTR + b + 1];
        basea[w] = s0;
        rl[w] = s1 - s0;
    }
    if (t < BKT_W) lcnt[t] = 0;
    __syncthreads();
    const int bs = wsum[0] + wsum[1] + wsum[2] + wsum[3];

    // --- scan rl (391 entries, 2/thread, wave-shuffle)
    int w0 = t * 2;
    int c0 = (w0 < NW) ? rl[w0] : 0;
    int c1 = (w0 + 1 < NW) ? rl[w0 + 1] : 0;
    int ts = c0 + c1;
    int sc = ts;
    #pragma unroll
    for (int off = 1; off < 64; off <<= 1) {
        int v = __shfl_up(sc, off, 64);
        if (lane >= off) sc += v;
    }
    __syncthreads();                       // all bs-reads done before wsum reuse
    if (lane == 63) wsum[wv] = sc;
    __syncthreads();
    int wo = 0;
    #pragma unroll
    for (int i = 0; i < 4; ++i) wo += (i < wv) ? wsum[i] : 0;
    const int total = wsum[0] + wsum[1] + wsum[2] + wsum[3];
    int excl0 = sc - ts + wo;
    if (w0 < NW)     pfx[w0]     = excl0;
    if (w0 + 1 < NW) pfx[w0 + 1] = excl0 + c0;
    __syncthreads();

    for (int w = t; w < NW; w += 256) {
        int p = pfx[w], len = rl[w];
        basea[w] = w * CH + basea[w] - p;
        for (int i = 0; i < len; ++i) map[p + i] = (unsigned short)w;
    }
    __syncthreads();
    for (int j = t; j < total; j += 256) {
        unsigned p = edgebuf[basea[map[j]] + j];
        atomicAdd(&lcnt[p & (BKT_W - 1)], 1);
    }
    __syncthreads();

    // --- 128-wide scan of lcnt: 2-wave shuffle scan, 1 barrier
    int myc = 0, sc2 = 0;
    if (t < BKT_W) {
        myc = lcnt[t];
        sc2 = myc;
        #pragma unroll
        for (int off = 1; off < 64; off <<= 1) {
            int v = __shfl_up(sc2, off, 64);
            if (lane >= off) sc2 += v;
        }
        if (t == 63) hs1 = sc2;
    }
    __syncthreads();
    if (t < BKT_W) {
        int excl = sc2 - myc + ((t >= 64) ? hs1 : 0);
        int node = b * BKT_W + t;
        if (node < NN) {
            rowstart[node] = bs + excl;
            dis[node] = rsqrtf((float)myc + 1.0f);
        }
        lcur[t] = bs + excl;
    }
    if (b == 0 && t == 0) rowstart[NN] = NE;
    __syncthreads();
    for (int j = t; j < total; j += 256) {
        unsigned p = edgebuf[basea[map[j]] + j];
        int pos = atomicAdd(&lcur[p & (BKT_W - 1)], 1);
        colidx[pos] = (int)(p >> BKT_SH);
    }
}

// ---------------- GEMM1: xs1 = bf16x2{(x @ W1) * dis}, 64B/node row ---------
__global__ __launch_bounds__(256) void k_gemm1(
    const float* __restrict__ x, const float* __restrict__ W1,
    const float* __restrict__ dis,
    unsigned* __restrict__ xs1)
{
    __shared__ float xls[128 * 33];
    __shared__ float wls[32 * 32];
    const int t = threadIdx.x;
    const int tc = t & 7;
    const int tr = t >> 3;
    const int base = blockIdx.x * 128;

    float a[4][4] = {};

    for (int k0 = 0; k0 < NF; k0 += 32) {
        {
            int i = t * 4;
            int kk = i >> 5, c = i & 31;
            *(float4*)&wls[kk * 32 + c] = *(const float4*)&W1[(k0 + kk) * C1 + c];
        }
        #pragma unroll
        for (int r = 0; r < 4; ++r) {
            int n = (t >> 3) + r * 32;
            int j = (t & 7) * 4;
            int node = base + n;
            float4 v = make_float4(0.f, 0.f, 0.f, 0.f);
            if (node < NN) v = *(const float4*)&x[(long long)node * NF + k0 + j];
            xls[n * 33 + j + 0] = v.x;
            xls[n * 33 + j + 1] = v.y;
            xls[n * 33 + j + 2] = v.z;
            xls[n * 33 + j + 3] = v.w;
        }
        __syncthreads();
        #pragma unroll 8
        for (int kk = 0; kk < 32; ++kk) {
            float4 w = *(const float4*)&wls[kk * 32 + tc * 4];
            #pragma unroll
            for (int i = 0; i < 4; ++i) {
                float xv = xls[(tr * 4 + i) * 33 + kk];
                a[i][0] = fmaf(xv, w.x, a[i][0]);
                a[i][1] = fmaf(xv, w.y, a[i][1]);
                a[i][2] = fmaf(xv, w.z, a[i][2]);
                a[i][3] = fmaf(xv, w.w, a[i][3]);
            }
        }
        __syncthreads();
    }
    #pragma unroll
    for (int i = 0; i < 4; ++i) {
        int node = base + tr * 4 + i;
        if (node < NN) {
            float dv = dis[node];
            uint2 o;
            o.x = pack_bf2(a[i][0] * dv, a[i][1] * dv);
            o.y = pack_bf2(a[i][2] * dv, a[i][3] * dv);
            *(uint2*)&xs1[node * 16 + tc * 2] = o;
        }
    }
}

// ---------------- gather layer1 + fused GEMM2 epilogue ----------------------
// 8 lanes/node, uint2 loads (measured-best topology: 3125 blocks, 12.5K waves),
// + software-pipelined colidx prefetch: next 8 indices load while current 8
// row-gathers are in flight -> dependent chain is one gather latency per round.
__global__ __launch_bounds__(256) void k_gather1(
    const unsigned* __restrict__ xs1, const int* __restrict__ colidx,
    const int* __restrict__ rowstart, const float* __restrict__ dis,
    const float* __restrict__ b1, const float* __restrict__ W2,
    unsigned* __restrict__ xs2b)
{
    __shared__ float w2s[C1 * C2];
    __shared__ float hrow[32 * 33];
    const int t = threadIdx.x;
    if (t < 128) *(float4*)&w2s[t * 4] = *(const float4*)&W2[t * 4];
    const int l = t & 7;
    const int n = t >> 3;
    const int v = blockIdx.x * 32 + n;   // NN = 100000 = 3125*32 exactly

    const int start = rowstart[v];
    const int num = rowstart[v + 1] - start;
    const int* __restrict__ cp = &colidx[start];
    const uint2* __restrict__ tb = (const uint2*)xs1;   // row v = tb[v*8 + l]
    float4 a0 = make_float4(0.f, 0.f, 0.f, 0.f);
    float4 a1 = a0, a2 = a0, a3 = a0;
    acc4(a0, tb[v * 8 + l]);                            // self loop
    int i = 0;
    if (num >= 8) {
        int idx[8];
        #pragma unroll
        for (int j = 0; j < 8; ++j) idx[j] = cp[j];
        for (; i + 16 <= num; i += 8) {
            int nx[8];
            #pragma unroll
            for (int j = 0; j < 8; ++j) nx[j] = cp[i + 8 + j];
            uint2 q[8];
            #pragma unroll
            for (int j = 0; j < 8; ++j) q[j] = tb[idx[j] * 8 + l];
            acc4(a0, q[0]); acc4(a1, q[1]); acc4(a2, q[2]); acc4(a3, q[3]);
            acc4(a0, q[4]); acc4(a1, q[5]); acc4(a2, q[6]); acc4(a3, q[7]);
            #pragma unroll
            for (int j = 0; j < 8; ++j) idx[j] = nx[j];
        }
        {   // drain the pipelined 8
            uint2 q[8];
            #pragma unroll
            for (int j = 0; j < 8; ++j) q[j] = tb[idx[j] * 8 + l];
            acc4(a0, q[0]); acc4(a1, q[1]); acc4(a2, q[2]); acc4(a3, q[3]);
            acc4(a0, q[4]); acc4(a1, q[5]); acc4(a2, q[6]); acc4(a3, q[7]);
            i += 8;
        }
    }
    for (; i < num; ++i) acc4(a0, tb[cp[i] * 8 + l]);
    float ax = (a0.x + a1.x) + (a2.x + a3.x);
    float ay = (a0.y + a1.y) + (a2.y + a3.y);
    float az = (a0.z + a1.z) + (a2.z + a3.z);
    float aw = (a0.w + a1.w) + (a2.w + a3.w);
    const float dv = dis[v];

    hrow[n * 33 + l * 4 + 0] = fmaxf(fmaf(ax, dv, b1[l * 4 + 0]), 0.f);
    hrow[n * 33 + l * 4 + 1] = fmaxf(fmaf(ay, dv, b1[l * 4 + 1]), 0.f);
    hrow[n * 33 + l * 4 + 2] = fmaxf(fmaf(az, dv, b1[l * 4 + 2]), 0.f);
    hrow[n * 33 + l * 4 + 3] = fmaxf(fmaf(aw, dv, b1[l * 4 + 3]), 0.f);
    __syncthreads();

    // GEMM2 epilogue: lane l computes output cols 2l, 2l+1
    const float* hr = &hrow[n * 33];
    float s0 = 0.f, s1 = 0.f;
    #pragma unroll
    for (int k = 0; k < 32; ++k) {
        float hv = hr[k];
        s0 = fmaf(hv, w2s[k * C2 + 2 * l + 0], s0);
        s1 = fmaf(hv, w2s[k * C2 + 2 * l + 1], s1);
    }
    xs2b[v * 8 + l] = pack_bf2(s0 * dv, s1 * dv);
}

// ---------------- gather layer2 + fused mean-pool ---------------------------
// 4 lanes/node, uint2 loads, index prefetch. Wave-uniform graph-id fast path:
// butterfly reduce across the wave's 16 nodes -> 16 LDS atomics/wave.
__global__ __launch_bounds__(256) void k_gather2(
    const unsigned* __restrict__ xs2b, const int* __restrict__ colidx,
    const int* __restrict__ rowstart, const float* __restrict__ dis,
    const int* __restrict__ batch,
    float* __restrict__ pool, float* __restrict__ cntf)
{
    __shared__ float psum[NG * C2];
    __shared__ float cs[NG];
    const int t = threadIdx.x;
    for (int i = t; i < NG * C2; i += 256) psum[i] = 0.f;
    if (t < NG) cs[t] = 0.f;
    __syncthreads();

    const int l = t & 3;
    const int n = t >> 2;                 // 0..63
    const int v = blockIdx.x * 64 + n;
    const bool valid = v < NN;
    const int lane = t & 63;

    float4 r = make_float4(0.f, 0.f, 0.f, 0.f);
    int g = 0;
    if (valid) {
        const int start = rowstart[v];
        const int num = rowstart[v + 1] - start;
        const int* __restrict__ cp = &colidx[start];
        const uint2* __restrict__ tb = (const uint2*)xs2b;  // row v = tb[v*4 + l]
        float4 a0 = make_float4(0.f, 0.f, 0.f, 0.f);
        float4 a1 = a0, a2 = a0, a3 = a0;
        acc4(a0, tb[v * 4 + l]);                            // self loop
        int i = 0;
        if (num >= 8) {
            int idx[8];
            #pragma unroll
            for (int j = 0; j < 8; ++j) idx[j] = cp[j];
            for (; i + 16 <= num; i += 8) {
                int nx[8];
                #pragma unroll
                for (int j = 0; j < 8; ++j) nx[j] = cp[i + 8 + j];
                uint2 q[8];
                #pragma unroll
                for (int j = 0; j < 8; ++j) q[j] = tb[idx[j] * 4 + l];
                acc4(a0, q[0]); acc4(a1, q[1]); acc4(a2, q[2]); acc4(a3, q[3]);
                acc4(a0, q[4]); acc4(a1, q[5]); acc4(a2, q[6]); acc4(a3, q[7]);
                #pragma unroll
                for (int j = 0; j < 8; ++j) idx[j] = nx[j];
            }
            {
                uint2 q[8];
                #pragma unroll
                for (int j = 0; j < 8; ++j) q[j] = tb[idx[j] * 4 + l];
                acc4(a0, q[0]); acc4(a1, q[1]); acc4(a2, q[2]); acc4(a3, q[3]);
                acc4(a0, q[4]); acc4(a1, q[5]); acc4(a2, q[6]); acc4(a3, q[7]);
                i += 8;
            }
        }
        for (; i < num; ++i) acc4(a0, tb[cp[i] * 4 + l]);
        float dv = dis[v];
        g = batch[v];
        r.x = ((a0.x + a1.x) + (a2.x + a3.x)) * dv;
        r.y = ((a0.y + a1.y) + (a2.y + a3.y)) * dv;
        r.z = ((a0.z + a1.z) + (a2.z + a3.z)) * dv;
        r.w = ((a0.w + a1.w) + (a2.w + a3.w)) * dv;
    }

    int g0 = __shfl(g, 0, 64);
    bool uni = __all(!valid || g == g0);
    if (uni) {
        float vv[4] = {r.x, r.y, r.z, r.w};
        #pragma unroll
        for (int j = 0; j < 4; ++j) {
            float val = vv[j];
            val += __shfl_xor(val, 4, 64);
            val += __shfl_xor(val, 8, 64);
            val += __shfl_xor(val, 16, 64);
            val += __shfl_xor(val, 32, 64);
            if (lane < 4) atomicAdd(&psum[g0 * C2 + lane * 4 + j], val);
        }
        unsigned long long mb = __ballot(valid && (l == 0));
        if (lane == 0 && mb) atomicAdd(&cs[g0], (float)__popcll(mb));
    } else {
        if (valid) {
            atomicAdd(&psum[g * C2 + l * 4 + 0], r.x);
            atomicAdd(&psum[g * C2 + l * 4 + 1], r.y);
            atomicAdd(&psum[g * C2 + l * 4 + 2], r.z);
            atomicAdd(&psum[g * C2 + l * 4 + 3], r.w);
            if (l == 0) atomicAdd(&cs[g], 1.0f);
        }
    }
    __syncthreads();
    for (int i = t; i < NG * C2; i += 256)
        if (psum[i] != 0.f) atomicAdd(&pool[i], psum[i]);
    if (t < NG && cs[t] != 0.f) atomicAdd(&cntf[t], cs[t]);
}

// ---------------- final: out[g] = (pool/cnt + b2) @ lw + lb -----------------
__global__ void k_final(const float* __restrict__ pool, const float* __restrict__ cntf,
                        const float* __restrict__ b2,
                        const float* __restrict__ lw, const float* __restrict__ lb,
                        float* __restrict__ out)
{
    int g = threadIdx.x;
    if (g < NG) {
        float c = fmaxf(cntf[g], 1.0f);
        float inv = 1.0f / c;
        float s = lb[0];
        #pragma unroll
        for (int k = 0; k < C2; ++k) {
            s = fmaf(b2[k], lw[k], s);                    // bias fold
            s = fmaf(pool[g * C2 + k] * inv, lw[k], s);
        }
        out[g] = s;
    }
}

extern "C" void kernel_launch(void* const* d_in, const int* in_sizes, int n_in,
                              void* d_out, int out_size, void* d_ws, size_t ws_size,
                              hipStream_t stream) {
    const float* x     = (const float*)d_in[0];
    const int*   ei    = (const int*)d_in[1];
    const int*   batch = (const int*)d_in[2];
    const float* W1    = (const float*)d_in[3];
    const float* b1    = (const float*)d_in[4];
    const float* W2    = (const float*)d_in[5];
    const float* b2    = (const float*)d_in[6];
    const float* lw    = (const float*)d_in[7];
    const float* lb    = (const float*)d_in[8];
    float* out = (float*)d_out;

    float*    wsf = (float*)d_ws;
    int*      wsi = (int*)d_ws;
    unsigned* wsu = (unsigned*)d_ws;

    int*      bcnt     = wsi + OFF_BCNT;
    float*    pool     = wsf + OFF_POOL;
    float*    cntf     = wsf + OFF_CNTF;
    int*      runstart = wsi + OFF_RUN;
    int*      rowstart = wsi + OFF_ROW;
    float*    dis      = wsf + OFF_DIS;
    unsigned* edgebuf  = wsu + OFF_EDG;
    unsigned* xs1      = wsu + OFF_XS1;    // aliases edgebuf (dead after fillfused)
    unsigned* xs2b     = wsu + OFF_XS2B;
    int*      colidx   = wsi + OFF_COL;

    const int* S = ei;            // edge_index[0] (src)
    const int* D = ei + NE;       // edge_index[1] (dst)

    hipMemsetAsync(wsi + OFF_BCNT, 0, 2304 * sizeof(int), stream);  // bcnt+pool+cntf

    k_part       <<<NW, 512, 0, stream>>>(S, D, edgebuf, runstart, bcnt);
    k_fillfused  <<<NBKT, 256, 0, stream>>>(edgebuf, runstart, bcnt, rowstart, dis, colidx);
    k_gemm1      <<<(NN + 127) / 128, 256, 0, stream>>>(x, W1, dis, xs1);
    k_gather1    <<<NN / 32, 256, 0, stream>>>(xs1, colidx, rowstart, dis, b1, W2, xs2b);
    k_gather2    <<<(NN + 63) / 64, 256, 0, stream>>>(xs2b, colidx, rowstart, dis, batch, pool, cntf);
    k_final      <<<1, 64, 0, stream>>>(pool, cntf, b2, lw, lb, out);
}